// Round 17
// baseline (717.919 us; speedup 1.0000x reference)
//
#include <hip/hip_runtime.h>
#include <stdint.h>

#define F 16
#define CDIM 320
#define DDIM 4096
#define NSEQ 8192
#define SEQS 4        // sequences per wave
#define THREADS 64    // 1 wave per block
#define NT 20
#define KS 10

typedef __attribute__((ext_vector_type(8))) short short8;
typedef __attribute__((ext_vector_type(4))) float f32x4;
typedef __attribute__((ext_vector_type(2))) unsigned int uint2v;
typedef __attribute__((ext_vector_type(4))) unsigned int uint4v;

__device__ __forceinline__ unsigned short f2bf(float f) {
    union { float f; uint32_t u; } v; v.f = f;
    uint32_t r = v.u + 0x7FFFu + ((v.u >> 16) & 1u);   // RTNE
    return (unsigned short)(r >> 16);
}
// [16][320] bf16 tile swizzle, row stride 640 B, 16B chunks, chunk^(row&7)
// bijective per row and in-bounds (40 chunks = 5 groups of 8).
__device__ __forceinline__ int swz(int row, int b) {
    return row * 640 + (b ^ ((row & 7) << 4));
}

// One-time: pack Wq/Wk/Wv/Wo (fp32 row-major [320][320]) into bf16 B-fragment
// order. Fragment (m, nt, ks) is a 1KB block: lane (g,lr) holds
// W[nt*16+lr][ks*32+g*8 .. +7]. Byte offset = ((m*NT+nt)*KS+ks)*1024 + lane*16.
__global__ __launch_bounds__(256)
void pack_weights_kernel(const float* __restrict__ Wq, const float* __restrict__ Wk,
                         const float* __restrict__ Wv, const float* __restrict__ Wo,
                         char* __restrict__ pk)
{
    const int t = blockIdx.x * 256 + threadIdx.x;
    if (t >= 4 * NT * KS * 64) return;
    const int lane = t & 63;
    const int rest = t >> 6;
    const int ks = rest % KS;
    const int nt = (rest / KS) % NT;
    const int m  = rest / (KS * NT);
    const float* W = (m == 0) ? Wq : (m == 1) ? Wk : (m == 2) ? Wv : Wo;
    const int g = lane >> 4, lr = lane & 15;
    const float* src = W + (size_t)(nt * 16 + lr) * CDIM + ks * 32 + g * 8;
    const f32x4 a = *(const f32x4*)src;
    const f32x4 b = *(const f32x4*)(src + 4);
    float vals[8] = {a[0], a[1], a[2], a[3], b[0], b[1], b[2], b[3]};
    short8 o;
#pragma unroll
    for (int j = 0; j < 8; ++j) o[j] = (short)f2bf(vals[j]);
    *(short8*)(pk + (size_t)t * 16) = o;
}

// 4 SEQS PER WAVE: the measured wall is the TCP instruction floor — each
// wave streams 800 x 1KB weight-fragment loads (~16 cyc of the CU's TCP
// pipe each); total = (seqs/2)/..., only amortization per register-load
// helps. k=2 (R16) -> k=4 halves it. 1 wave/block, 80KB LDS -> 2 blocks/CU.
// launch_bounds(64,1): 512-VGPR cap, peak live ~390 -> spill-impossible.
// All seq-indexed arrays only inside fully-unrolled loops (rule #20).
__global__ __launch_bounds__(THREADS, 1)
void temporal_attn_kernel(const float* __restrict__ hs,
                          const char* __restrict__ wpk,
                          const float* __restrict__ bo,
                          float* __restrict__ out)
{
    extern __shared__ __align__(16) char smem[];
    const int lane = threadIdx.x & 63;
    const int g    = lane >> 4;
    const int lr   = lane & 15;

    const int seq0 = blockIdx.x * SEQS;   // 4-aligned; never crosses bi bound
    const int bi  = seq0 >> 12;
    const int di  = seq0 & (DDIM - 1);

    char* kb[SEQS];   // per seq: Q, then V' (transposed)
    char* vb[SEQS];   // per seq: K, then attn-out
#pragma unroll
    for (int s = 0; s < SEQS; ++s) {
        kb[s] = smem + s * 20480;
        vb[s] = kb[s] + 10240;
    }

    // ---- load x rows for all seqs, add PE (trig once), pack bf16 ----
    const float* xrow0 = hs + ((size_t)(bi * F + lr) * DDIM + di) * CDIM;
    short8 axk[SEQS][KS];
#pragma unroll
    for (int ks = 0; ks < KS; ++ks) {
        const int k0 = ks * 32 + g * 8;
        float sn[4], cs[4];
#pragma unroll
        for (int jj = 0; jj < 4; ++jj) {
            const float c0 = (float)(k0 + 2 * jj);
            const float dv = __expf(c0 * -0.028782313662425575f); // -ln(1e4)/320
            const float ang = (float)lr * dv;                      // pos = frame
            sn[jj] = __sinf(ang);  cs[jj] = __cosf(ang);
        }
#pragma unroll
        for (int s = 0; s < SEQS; ++s) {
            const float* xr = xrow0 + s * CDIM;
            const f32x4 a = __builtin_nontemporal_load((const f32x4*)(xr + k0));
            const f32x4 b = __builtin_nontemporal_load((const f32x4*)(xr + k0 + 4));
            float xv[8] = {a[0], a[1], a[2], a[3], b[0], b[1], b[2], b[3]};
#pragma unroll
            for (int jj = 0; jj < 4; ++jj) {
                xv[2 * jj]     += sn[jj];
                xv[2 * jj + 1] += cs[jj];
            }
            short8 t;
#pragma unroll
            for (int j = 0; j < 8; ++j) t[j] = (short)f2bf(xv[j]);
            axk[s][ks] = t;
        }
    }

    // ---- projection: each fragment load feeds 4 MFMAs; prefetch dist 2 ----
    // mode 0: standard swizzled [16][640B]; mode 1: V' [320 cols][32B records]
    auto proj = [&](int m, char* const* dst, int mode) {
        const char* base = wpk + lane * 16 + (size_t)(m * NT) * KS * 1024;
        short8 f0[KS], f1[KS], f2[KS], f3[KS];
#pragma unroll
        for (int ks = 0; ks < KS; ++ks) {
            f0[ks] = *(const short8*)(base + (size_t)ks * 1024);
            f1[ks] = *(const short8*)(base + (size_t)(KS + ks) * 1024);
        }
        auto storeT = [&](int ti, const f32x4* acc) {
            const int c = ti * 16 + lr;
            if (mode == 0) {
#pragma unroll
                for (int s = 0; s < SEQS; ++s)
#pragma unroll
                    for (int r = 0; r < 4; ++r)
                        *(short*)(dst[s] + swz(g * 4 + r, c * 2)) = (short)f2bf(acc[s][r]);
            } else {
#pragma unroll
                for (int s = 0; s < SEQS; ++s)
#pragma unroll
                    for (int r = 0; r < 4; ++r)
                        *(short*)(dst[s] + c * 32 + (g * 4 + r) * 2) = (short)f2bf(acc[s][r]);
            }
        };
#pragma unroll 1
        for (int np2 = 0; np2 < 5; ++np2) {
            const int t = np2 * 4;
#pragma unroll
            for (int ks = 0; ks < KS; ++ks) {
                f2[ks] = *(const short8*)(base + (size_t)((t + 2) * KS + ks) * 1024);
                f3[ks] = *(const short8*)(base + (size_t)((t + 3) * KS + ks) * 1024);
            }
            {
                f32x4 a0[SEQS], a1[SEQS];
#pragma unroll
                for (int s = 0; s < SEQS; ++s) { a0[s] = {0,0,0,0}; a1[s] = {0,0,0,0}; }
#pragma unroll
                for (int ks = 0; ks < KS; ++ks)
#pragma unroll
                    for (int s = 0; s < SEQS; ++s) {
                        a0[s] = __builtin_amdgcn_mfma_f32_16x16x32_bf16(axk[s][ks], f0[ks], a0[s], 0, 0, 0);
                        a1[s] = __builtin_amdgcn_mfma_f32_16x16x32_bf16(axk[s][ks], f1[ks], a1[s], 0, 0, 0);
                    }
                storeT(t, a0);
                storeT(t + 1, a1);
            }
            if (np2 < 4) {
#pragma unroll
                for (int ks = 0; ks < KS; ++ks) {
                    f0[ks] = *(const short8*)(base + (size_t)((t + 4) * KS + ks) * 1024);
                    f1[ks] = *(const short8*)(base + (size_t)((t + 5) * KS + ks) * 1024);
                }
            }
            {
                f32x4 a2[SEQS], a3[SEQS];
#pragma unroll
                for (int s = 0; s < SEQS; ++s) { a2[s] = {0,0,0,0}; a3[s] = {0,0,0,0}; }
#pragma unroll
                for (int ks = 0; ks < KS; ++ks)
#pragma unroll
                    for (int s = 0; s < SEQS; ++s) {
                        a2[s] = __builtin_amdgcn_mfma_f32_16x16x32_bf16(axk[s][ks], f2[ks], a2[s], 0, 0, 0);
                        a3[s] = __builtin_amdgcn_mfma_f32_16x16x32_bf16(axk[s][ks], f3[ks], a3[s], 0, 0, 0);
                    }
                storeT(t + 2, a2);
                storeT(t + 3, a3);
            }
        }
    };

    proj(0, kb, 0);   // Q
    proj(1, vb, 0);   // K

    // ---- scores via MFMA (S^T = mfma(K, Q)), all seqs interleaved ----
    const float scale = 0.15811388300841897f;  // 40^-0.5
    const short8 z8 = {0, 0, 0, 0, 0, 0, 0, 0};
    uint2v ppk[SEQS][8];
#pragma unroll
    for (int h = 0; h < 8; ++h) {
        const int cb = h * 80;
#pragma unroll
        for (int s = 0; s < SEQS; ++s) {
            short8 kf  = *(const short8*)(vb[s] + swz(lr, cb + g * 16));
            short8 qf  = *(const short8*)(kb[s] + swz(lr, cb + g * 16));
            short8 kt8 = *(const short8*)(vb[s] + swz(lr, cb + 64));   // ch 32..39
            short8 qt8 = *(const short8*)(kb[s] + swz(lr, cb + 64));
            short8 kt = (g == 0) ? kt8 : z8;   // zero-pad K=40 -> 32+8
            short8 qt = (g == 0) ? qt8 : z8;
            f32x4 c = {0.f, 0.f, 0.f, 0.f};
            c = __builtin_amdgcn_mfma_f32_16x16x32_bf16(kf, qf, c, 0, 0, 0);
            c = __builtin_amdgcn_mfma_f32_16x16x32_bf16(kt, qt, c, 0, 0, 0);
            float sv[4];
            float m4 = -1e30f;
#pragma unroll
            for (int r = 0; r < 4; ++r) {
                sv[r] = (g * 4 + r <= lr) ? c[r] * scale : -1e30f;   // causal
                m4 = fmaxf(m4, sv[r]);
            }
            m4 = fmaxf(m4, __shfl_xor(m4, 16));
            m4 = fmaxf(m4, __shfl_xor(m4, 32));
            float sum = 0.f;
#pragma unroll
            for (int r = 0; r < 4; ++r) { sv[r] = __expf(sv[r] - m4); sum += sv[r]; }
            sum += __shfl_xor(sum, 16);
            sum += __shfl_xor(sum, 32);
            const float inv = 1.f / sum;
            uint2v pk;
            pk[0] = (uint32_t)f2bf(sv[0] * inv) | ((uint32_t)f2bf(sv[1] * inv) << 16);
            pk[1] = (uint32_t)f2bf(sv[2] * inv) | ((uint32_t)f2bf(sv[3] * inv) << 16);
            ppk[s][h] = pk;
        }
    }

    proj(2, kb, 1);   // V' (transposed [320][32B]) over Q

    // ---- PV via MFMA; attn-out -> vb (K dead); seqs interleaved ----
#pragma unroll
    for (int h = 0; h < 8; ++h) {
#pragma unroll
        for (int s = 0; s < SEQS; ++s) {
            uint2v own = ppk[s][h];
            uint2v x16;
            x16[0] = (uint32_t)__shfl_xor((int)own[0], 16);
            x16[1] = (uint32_t)__shfl_xor((int)own[1], 16);
            uint4v pair;
            pair[0] = ((g & 1) == 0) ? own[0] : x16[0];   // keys (g>>1)*8 .. +3
            pair[1] = ((g & 1) == 0) ? own[1] : x16[1];
            pair[2] = ((g & 1) == 0) ? x16[0] : own[0];   // keys (g>>1)*8+4 .. +7
            pair[3] = ((g & 1) == 0) ? x16[1] : own[1];
            uint4v rec;
#pragma unroll
            for (int i = 0; i < 4; ++i) rec[i] = (uint32_t)__shfl_xor((int)pair[i], 32);
            uint4v af4;
#pragma unroll
            for (int i = 0; i < 4; ++i)
                af4[i] = (g == 0) ? pair[i] : (g == 1) ? rec[i] : 0u;
            const short8 af = *(const short8*)&af4;
#pragma unroll
            for (int t = 0; t < 3; ++t) {
                const int lcol = (t == 2) ? (lr & 7) : lr;   // dup cols not written
                const int col  = h * 40 + t * 16 + lcol;
                const short8 bf = *(const short8*)(kb[s] + col * 32 + g * 16);
                f32x4 o = {0.f, 0.f, 0.f, 0.f};
                o = __builtin_amdgcn_mfma_f32_16x16x32_bf16(af, bf, o, 0, 0, 0);
                if (t < 2 || lr < 8) {
#pragma unroll
                    for (int r = 0; r < 4; ++r)
                        *(short*)(vb[s] + swz(g * 4 + r, col * 2)) = (short)f2bf(o[r]);
                }
            }
        }
    }

    // ---- output projection: shared Wo fragments feed 4 seqs ----
    short8 aof[SEQS][KS];
#pragma unroll
    for (int ks = 0; ks < KS; ++ks)
#pragma unroll
        for (int s = 0; s < SEQS; ++s)
            aof[s][ks] = *(const short8*)(vb[s] + swz(lr, ks * 64 + g * 16));
    {
        const char* base = wpk + lane * 16 + (size_t)(3 * NT) * KS * 1024;
        short8 f0[KS], f1[KS], f2[KS], f3[KS];
#pragma unroll
        for (int ks = 0; ks < KS; ++ks) {
            f0[ks] = *(const short8*)(base + (size_t)ks * 1024);
            f1[ks] = *(const short8*)(base + (size_t)(KS + ks) * 1024);
        }
        auto outStore2 = [&](int t0, const f32x4* accL, const f32x4* accH) {
            // tiles t0, t0+1 (t0 even): cols c0,c1 cover one 128B line per row
            const int c0 = t0 * 16 + lr;
            const int c1 = c0 + 16;
            const float bias0 = bo[c0];
            const float bias1 = bo[c1];
#pragma unroll
            for (int s = 0; s < SEQS; ++s)
#pragma unroll
                for (int r = 0; r < 4; ++r) {
                    float* rowp = out + ((size_t)(bi * F + g * 4 + r) * DDIM + di + s) * CDIM;
                    rowp[c0] = accL[s][r] + bias0;
                    rowp[c1] = accH[s][r] + bias1;
                }
        };
#pragma unroll 1
        for (int np2 = 0; np2 < 5; ++np2) {
            const int t = np2 * 4;
#pragma unroll
            for (int ks = 0; ks < KS; ++ks) {
                f2[ks] = *(const short8*)(base + (size_t)((t + 2) * KS + ks) * 1024);
                f3[ks] = *(const short8*)(base + (size_t)((t + 3) * KS + ks) * 1024);
            }
            {
                f32x4 a0[SEQS], a1[SEQS];
#pragma unroll
                for (int s = 0; s < SEQS; ++s) { a0[s] = {0,0,0,0}; a1[s] = {0,0,0,0}; }
#pragma unroll
                for (int ks = 0; ks < KS; ++ks)
#pragma unroll
                    for (int s = 0; s < SEQS; ++s) {
                        a0[s] = __builtin_amdgcn_mfma_f32_16x16x32_bf16(aof[s][ks], f0[ks], a0[s], 0, 0, 0);
                        a1[s] = __builtin_amdgcn_mfma_f32_16x16x32_bf16(aof[s][ks], f1[ks], a1[s], 0, 0, 0);
                    }
                outStore2(t, a0, a1);
            }
            if (np2 < 4) {
#pragma unroll
                for (int ks = 0; ks < KS; ++ks) {
                    f0[ks] = *(const short8*)(base + (size_t)((t + 4) * KS + ks) * 1024);
                    f1[ks] = *(const short8*)(base + (size_t)((t + 5) * KS + ks) * 1024);
                }
            }
            {
                f32x4 a2[SEQS], a3[SEQS];
#pragma unroll
                for (int s = 0; s < SEQS; ++s) { a2[s] = {0,0,0,0}; a3[s] = {0,0,0,0}; }
#pragma unroll
                for (int ks = 0; ks < KS; ++ks)
#pragma unroll
                    for (int s = 0; s < SEQS; ++s) {
                        a2[s] = __builtin_amdgcn_mfma_f32_16x16x32_bf16(aof[s][ks], f2[ks], a2[s], 0, 0, 0);
                        a3[s] = __builtin_amdgcn_mfma_f32_16x16x32_bf16(aof[s][ks], f3[ks], a3[s], 0, 0, 0);
                    }
                outStore2(t + 2, a2, a3);
            }
        }
    }
}

extern "C" void kernel_launch(void* const* d_in, const int* in_sizes, int n_in,
                              void* d_out, int out_size, void* d_ws, size_t ws_size,
                              hipStream_t stream) {
    const float* hs = (const float*)d_in[0];
    const float* Wq = (const float*)d_in[1];
    const float* Wk = (const float*)d_in[2];
    const float* Wv = (const float*)d_in[3];
    const float* Wo = (const float*)d_in[4];
    const float* bo = (const float*)d_in[5];
    float* out = (float*)d_out;
    char* wpk = (char*)d_ws;   // 4*200*1024 = 819200 B of packed bf16 weights

    pack_weights_kernel<<<dim3((4 * NT * KS * 64 + 255) / 256), dim3(256), 0, stream>>>(
        Wq, Wk, Wv, Wo, wpk);

    const int lds = SEQS * 20480;   // 81920 B -> exactly 2 blocks/CU
    (void)hipFuncSetAttribute((const void*)temporal_attn_kernel,
                              hipFuncAttributeMaxDynamicSharedMemorySize, lds);
    temporal_attn_kernel<<<dim3(NSEQ / SEQS), dim3(THREADS), lds, stream>>>(
        hs, wpk, bo, out);
}

// Round 18
// 221.755 us; speedup vs baseline: 3.2374x; 3.2374x over previous
//
#include <hip/hip_runtime.h>
#include <stdint.h>

#define F 16
#define CDIM 320
#define DDIM 4096
#define NSEQ 8192
#define THREADS 128   // 2 waves/block; each wave owns 2 sequences
#define NT 20
#define KS 10

typedef __attribute__((ext_vector_type(8))) short short8;
typedef __attribute__((ext_vector_type(4))) float f32x4;
typedef __attribute__((ext_vector_type(2))) unsigned int uint2v;
typedef __attribute__((ext_vector_type(4))) unsigned int uint4v;

__device__ __forceinline__ unsigned short f2bf(float f) {
    union { float f; uint32_t u; } v; v.f = f;
    uint32_t r = v.u + 0x7FFFu + ((v.u >> 16) & 1u);   // RTNE
    return (unsigned short)(r >> 16);
}
// [16][320] bf16 tile swizzle, row stride 640 B, 16B chunks, chunk^(row&7)
// bijective per row and in-bounds (40 chunks = 5 groups of 8).
__device__ __forceinline__ int swz(int row, int b) {
    return row * 640 + (b ^ ((row & 7) << 4));
}

// One-time: pack Wq/Wk/Wv/Wo (fp32 row-major [320][320]) into bf16 B-fragment
// order. Fragment (m, nt, ks) is a 1KB block: lane (g,lr) holds
// W[nt*16+lr][ks*32+g*8 .. +7]. Byte offset = ((m*NT+nt)*KS+ks)*1024 + lane*16.
__global__ __launch_bounds__(256)
void pack_weights_kernel(const float* __restrict__ Wq, const float* __restrict__ Wk,
                         const float* __restrict__ Wv, const float* __restrict__ Wo,
                         char* __restrict__ pk)
{
    const int t = blockIdx.x * 256 + threadIdx.x;
    if (t >= 4 * NT * KS * 64) return;
    const int lane = t & 63;
    const int rest = t >> 6;
    const int ks = rest % KS;
    const int nt = (rest / KS) % NT;
    const int m  = rest / (KS * NT);
    const float* W = (m == 0) ? Wq : (m == 1) ? Wk : (m == 2) ? Wv : Wo;
    const int g = lane >> 4, lr = lane & 15;
    const float* src = W + (size_t)(nt * 16 + lr) * CDIM + ks * 32 + g * 8;
    const f32x4 a = *(const f32x4*)src;
    const f32x4 b = *(const f32x4*)(src + 4);
    float vals[8] = {a[0], a[1], a[2], a[3], b[0], b[1], b[2], b[3]};
    short8 o;
#pragma unroll
    for (int j = 0; j < 8; ++j) o[j] = (short)f2bf(vals[j]);
    *(short8*)(pk + (size_t)t * 16) = o;
}

// CONVERGED CONFIG (exact R16, session best: 222us reported / 299 profiled,
// VGPR 200, clean). Amortization curve measured: 1 seq/wave=373, 2=299,
// 4=718 (R17: 2 waves/CU on 2/4 SIMDs + arch-VGPR ceiling is 256 not 512 ->
// spills). k=2 at 4 waves/CU is the optimum of this family.
//  - prefetch distance 2 in all weight passes (4 fragment arrays)
//  - MFMA attention (S^T = mfma(K,Q); PV with transposed V'), seqs interleaved
//  - paired 128B-line output stores
__global__ __launch_bounds__(THREADS, 1)
void temporal_attn_kernel(const float* __restrict__ hs,
                          const char* __restrict__ wpk,
                          const float* __restrict__ bo,
                          float* __restrict__ out)
{
    extern __shared__ __align__(16) char smem[];
    const int tid  = threadIdx.x;
    const int lane = tid & 63;
    const int wave = tid >> 6;
    const int g    = lane >> 4;
    const int lr   = lane & 15;

    const int seqA = blockIdx.x * 4 + wave * 2;   // seqB = seqA + 1, same bi
    const int bi  = seqA >> 12;
    const int di  = seqA & (DDIM - 1);

    char* const kbufA = smem + wave * 40960;   // seq A: Q, then V'
    char* const vbufA = kbufA + 10240;         // seq A: K, then attn-out
    char* const kbufB = kbufA + 20480;         // seq B: Q, then V'
    char* const vbufB = kbufA + 30720;         // seq B: K, then attn-out

    // ---- load x rows for BOTH seqs, add PE (trig computed once), pack bf16 ----
    const float* xrowA = hs + ((size_t)(bi * F + lr) * DDIM + di) * CDIM;
    const float* xrowB = xrowA + CDIM;         // seqB = seqA+1 -> +320 floats
    short8 axkA[KS], axkB[KS];
#pragma unroll
    for (int ks = 0; ks < KS; ++ks) {
        const int k0 = ks * 32 + g * 8;
        const f32x4 aA = __builtin_nontemporal_load((const f32x4*)(xrowA + k0));
        const f32x4 bA = __builtin_nontemporal_load((const f32x4*)(xrowA + k0 + 4));
        const f32x4 aB = __builtin_nontemporal_load((const f32x4*)(xrowB + k0));
        const f32x4 bB = __builtin_nontemporal_load((const f32x4*)(xrowB + k0 + 4));
        float xvA[8] = {aA[0], aA[1], aA[2], aA[3], bA[0], bA[1], bA[2], bA[3]};
        float xvB[8] = {aB[0], aB[1], aB[2], aB[3], bB[0], bB[1], bB[2], bB[3]};
#pragma unroll
        for (int jj = 0; jj < 4; ++jj) {
            const float c0 = (float)(k0 + 2 * jj);
            const float dv = __expf(c0 * -0.028782313662425575f); // -ln(1e4)/320
            const float ang = (float)lr * dv;                      // pos = frame
            const float sn = __sinf(ang), cs = __cosf(ang);        // PE: seq-indep
            xvA[2 * jj] += sn;  xvA[2 * jj + 1] += cs;
            xvB[2 * jj] += sn;  xvB[2 * jj + 1] += cs;
        }
        short8 tA, tB;
#pragma unroll
        for (int j = 0; j < 8; ++j) { tA[j] = (short)f2bf(xvA[j]); tB[j] = (short)f2bf(xvB[j]); }
        axkA[ks] = tA;  axkB[ks] = tB;
    }

    // ---- projection: shared fragments feed both seqs; prefetch distance 2 ----
    // mode 0: standard swizzled [16][640B]; mode 1: V' [320 cols][32B records]
    auto proj = [&](int m, char* dA, char* dB, int mode) {
        const char* base = wpk + lane * 16 + (size_t)(m * NT) * KS * 1024;
        short8 f0[KS], f1[KS], f2[KS], f3[KS];
#pragma unroll
        for (int ks = 0; ks < KS; ++ks) {
            f0[ks] = *(const short8*)(base + (size_t)ks * 1024);
            f1[ks] = *(const short8*)(base + (size_t)(KS + ks) * 1024);
        }
        auto store2 = [&](int ti, const f32x4& aA, const f32x4& aB) {
            const int c = ti * 16 + lr;
            if (mode == 0) {
#pragma unroll
                for (int r = 0; r < 4; ++r) {
                    const int row = g * 4 + r;
                    *(short*)(dA + swz(row, c * 2)) = (short)f2bf(aA[r]);
                    *(short*)(dB + swz(row, c * 2)) = (short)f2bf(aB[r]);
                }
            } else {
#pragma unroll
                for (int r = 0; r < 4; ++r) {
                    const int key = g * 4 + r;
                    *(short*)(dA + c * 32 + key * 2) = (short)f2bf(aA[r]);
                    *(short*)(dB + c * 32 + key * 2) = (short)f2bf(aB[r]);
                }
            }
        };
#pragma unroll 1
        for (int np2 = 0; np2 < 5; ++np2) {
            const int t = np2 * 4;
            // prefetch tiles t+2, t+3 (consumed after ~40 MFMAs + stores)
#pragma unroll
            for (int ks = 0; ks < KS; ++ks) {
                f2[ks] = *(const short8*)(base + (size_t)((t + 2) * KS + ks) * 1024);
                f3[ks] = *(const short8*)(base + (size_t)((t + 3) * KS + ks) * 1024);
            }
            {
                f32x4 a0A = {0,0,0,0}, a0B = {0,0,0,0}, a1A = {0,0,0,0}, a1B = {0,0,0,0};
#pragma unroll
                for (int ks = 0; ks < KS; ++ks) {
                    a0A = __builtin_amdgcn_mfma_f32_16x16x32_bf16(axkA[ks], f0[ks], a0A, 0, 0, 0);
                    a0B = __builtin_amdgcn_mfma_f32_16x16x32_bf16(axkB[ks], f0[ks], a0B, 0, 0, 0);
                    a1A = __builtin_amdgcn_mfma_f32_16x16x32_bf16(axkA[ks], f1[ks], a1A, 0, 0, 0);
                    a1B = __builtin_amdgcn_mfma_f32_16x16x32_bf16(axkB[ks], f1[ks], a1B, 0, 0, 0);
                }
                store2(t,     a0A, a0B);
                store2(t + 1, a1A, a1B);
            }
            if (np2 < 4) {   // prefetch tiles t+4, t+5
#pragma unroll
                for (int ks = 0; ks < KS; ++ks) {
                    f0[ks] = *(const short8*)(base + (size_t)((t + 4) * KS + ks) * 1024);
                    f1[ks] = *(const short8*)(base + (size_t)((t + 5) * KS + ks) * 1024);
                }
            }
            {
                f32x4 a2A = {0,0,0,0}, a2B = {0,0,0,0}, a3A = {0,0,0,0}, a3B = {0,0,0,0};
#pragma unroll
                for (int ks = 0; ks < KS; ++ks) {
                    a2A = __builtin_amdgcn_mfma_f32_16x16x32_bf16(axkA[ks], f2[ks], a2A, 0, 0, 0);
                    a2B = __builtin_amdgcn_mfma_f32_16x16x32_bf16(axkB[ks], f2[ks], a2B, 0, 0, 0);
                    a3A = __builtin_amdgcn_mfma_f32_16x16x32_bf16(axkA[ks], f3[ks], a3A, 0, 0, 0);
                    a3B = __builtin_amdgcn_mfma_f32_16x16x32_bf16(axkB[ks], f3[ks], a3B, 0, 0, 0);
                }
                store2(t + 2, a2A, a2B);
                store2(t + 3, a3A, a3B);
            }
        }
    };

    proj(0, kbufA, kbufB, 0);   // Q
    proj(1, vbufA, vbufB, 0);   // K

    // ---- scores via MFMA (S^T = mfma(K, Q)), seqs A and B interleaved ----
    const float scale = 0.15811388300841897f;  // 40^-0.5
    const short8 z8 = {0, 0, 0, 0, 0, 0, 0, 0};
    uint2v ppkA[8], ppkB[8];
#pragma unroll
    for (int h = 0; h < 8; ++h) {
        const int cb = h * 80;
        short8 kfA = *(const short8*)(vbufA + swz(lr, cb + g * 16));
        short8 qfA = *(const short8*)(kbufA + swz(lr, cb + g * 16));
        short8 kfB = *(const short8*)(vbufB + swz(lr, cb + g * 16));
        short8 qfB = *(const short8*)(kbufB + swz(lr, cb + g * 16));
        short8 ktA8 = *(const short8*)(vbufA + swz(lr, cb + 64));
        short8 qtA8 = *(const short8*)(kbufA + swz(lr, cb + 64));
        short8 ktB8 = *(const short8*)(vbufB + swz(lr, cb + 64));
        short8 qtB8 = *(const short8*)(kbufB + swz(lr, cb + 64));
        short8 ktA = (g == 0) ? ktA8 : z8;   // zero-pad K=40 -> 32+8
        short8 qtA = (g == 0) ? qtA8 : z8;
        short8 ktB = (g == 0) ? ktB8 : z8;
        short8 qtB = (g == 0) ? qtB8 : z8;
        f32x4 cA = {0,0,0,0}, cB = {0,0,0,0};
        cA = __builtin_amdgcn_mfma_f32_16x16x32_bf16(kfA, qfA, cA, 0, 0, 0);
        cB = __builtin_amdgcn_mfma_f32_16x16x32_bf16(kfB, qfB, cB, 0, 0, 0);
        cA = __builtin_amdgcn_mfma_f32_16x16x32_bf16(ktA, qtA, cA, 0, 0, 0);
        cB = __builtin_amdgcn_mfma_f32_16x16x32_bf16(ktB, qtB, cB, 0, 0, 0);
        float svA[4], svB[4];
        float mA = -1e30f, mB = -1e30f;
#pragma unroll
        for (int r = 0; r < 4; ++r) {
            const bool ok = (g * 4 + r <= lr);
            svA[r] = ok ? cA[r] * scale : -1e30f;
            svB[r] = ok ? cB[r] * scale : -1e30f;
            mA = fmaxf(mA, svA[r]);
            mB = fmaxf(mB, svB[r]);
        }
        mA = fmaxf(mA, __shfl_xor(mA, 16));  mB = fmaxf(mB, __shfl_xor(mB, 16));
        mA = fmaxf(mA, __shfl_xor(mA, 32));  mB = fmaxf(mB, __shfl_xor(mB, 32));
        float sumA = 0.f, sumB = 0.f;
#pragma unroll
        for (int r = 0; r < 4; ++r) {
            svA[r] = __expf(svA[r] - mA);  sumA += svA[r];
            svB[r] = __expf(svB[r] - mB);  sumB += svB[r];
        }
        sumA += __shfl_xor(sumA, 16);  sumB += __shfl_xor(sumB, 16);
        sumA += __shfl_xor(sumA, 32);  sumB += __shfl_xor(sumB, 32);
        const float invA = 1.f / sumA, invB = 1.f / sumB;
        uint2v pkA, pkB;
        pkA[0] = (uint32_t)f2bf(svA[0] * invA) | ((uint32_t)f2bf(svA[1] * invA) << 16);
        pkA[1] = (uint32_t)f2bf(svA[2] * invA) | ((uint32_t)f2bf(svA[3] * invA) << 16);
        pkB[0] = (uint32_t)f2bf(svB[0] * invB) | ((uint32_t)f2bf(svB[1] * invB) << 16);
        pkB[1] = (uint32_t)f2bf(svB[2] * invB) | ((uint32_t)f2bf(svB[3] * invB) << 16);
        ppkA[h] = pkA;
        ppkB[h] = pkB;
    }

    proj(2, kbufA, kbufB, 1);   // V' (transposed [320][32B]) over Q

    // ---- PV via MFMA; attn-out -> vbuf (K dead); seqs interleaved ----
#pragma unroll
    for (int h = 0; h < 8; ++h) {
        short8 afA, afB;
        {
            uint2v own = ppkA[h];
            uint2v x16;
            x16[0] = (uint32_t)__shfl_xor((int)own[0], 16);
            x16[1] = (uint32_t)__shfl_xor((int)own[1], 16);
            uint4v pair;
            pair[0] = ((g & 1) == 0) ? own[0] : x16[0];
            pair[1] = ((g & 1) == 0) ? own[1] : x16[1];
            pair[2] = ((g & 1) == 0) ? x16[0] : own[0];
            pair[3] = ((g & 1) == 0) ? x16[1] : own[1];
            uint4v rec;
#pragma unroll
            for (int i = 0; i < 4; ++i) rec[i] = (uint32_t)__shfl_xor((int)pair[i], 32);
            uint4v af4;
#pragma unroll
            for (int i = 0; i < 4; ++i)
                af4[i] = (g == 0) ? pair[i] : (g == 1) ? rec[i] : 0u;
            afA = *(const short8*)&af4;
        }
        {
            uint2v own = ppkB[h];
            uint2v x16;
            x16[0] = (uint32_t)__shfl_xor((int)own[0], 16);
            x16[1] = (uint32_t)__shfl_xor((int)own[1], 16);
            uint4v pair;
            pair[0] = ((g & 1) == 0) ? own[0] : x16[0];
            pair[1] = ((g & 1) == 0) ? own[1] : x16[1];
            pair[2] = ((g & 1) == 0) ? x16[0] : own[0];
            pair[3] = ((g & 1) == 0) ? x16[1] : own[1];
            uint4v rec;
#pragma unroll
            for (int i = 0; i < 4; ++i) rec[i] = (uint32_t)__shfl_xor((int)pair[i], 32);
            uint4v af4;
#pragma unroll
            for (int i = 0; i < 4; ++i)
                af4[i] = (g == 0) ? pair[i] : (g == 1) ? rec[i] : 0u;
            afB = *(const short8*)&af4;
        }
#pragma unroll
        for (int t = 0; t < 3; ++t) {
            const int lcol = (t == 2) ? (lr & 7) : lr;
            const int col  = h * 40 + t * 16 + lcol;
            const short8 bfA = *(const short8*)(kbufA + col * 32 + g * 16);
            const short8 bfB = *(const short8*)(kbufB + col * 32 + g * 16);
            f32x4 oA = {0,0,0,0}, oB = {0,0,0,0};
            oA = __builtin_amdgcn_mfma_f32_16x16x32_bf16(afA, bfA, oA, 0, 0, 0);
            oB = __builtin_amdgcn_mfma_f32_16x16x32_bf16(afB, bfB, oB, 0, 0, 0);
            if (t < 2 || lr < 8) {
#pragma unroll
                for (int r = 0; r < 4; ++r) {
                    *(short*)(vbufA + swz(g * 4 + r, col * 2)) = (short)f2bf(oA[r]);
                    *(short*)(vbufB + swz(g * 4 + r, col * 2)) = (short)f2bf(oB[r]);
                }
            }
        }
    }

    // ---- output projection: shared Wo fragments, prefetch distance 2 ----
    short8 aofA[KS], aofB[KS];
#pragma unroll
    for (int ks = 0; ks < KS; ++ks) {
        aofA[ks] = *(const short8*)(vbufA + swz(lr, ks * 64 + g * 16));
        aofB[ks] = *(const short8*)(vbufB + swz(lr, ks * 64 + g * 16));
    }
    {
        const char* base = wpk + lane * 16 + (size_t)(3 * NT) * KS * 1024;
        short8 f0[KS], f1[KS], f2[KS], f3[KS];
#pragma unroll
        for (int ks = 0; ks < KS; ++ks) {
            f0[ks] = *(const short8*)(base + (size_t)ks * 1024);
            f1[ks] = *(const short8*)(base + (size_t)(KS + ks) * 1024);
        }
        auto outStore2 = [&](int t0, const f32x4& aA, const f32x4& bA,
                             const f32x4& aB, const f32x4& bB) {
            // tiles t0, t0+1 (t0 even): cols c0,c1 cover one 128B line per row
            const int c0 = t0 * 16 + lr;
            const int c1 = c0 + 16;
            const float bias0 = bo[c0];
            const float bias1 = bo[c1];
#pragma unroll
            for (int r = 0; r < 4; ++r) {
                float* rowpA = out + ((size_t)(bi * F + g * 4 + r) * DDIM + di) * CDIM;
                float* rowpB = rowpA + CDIM;
                rowpA[c0] = aA[r] + bias0;
                rowpA[c1] = bA[r] + bias1;
                rowpB[c0] = aB[r] + bias0;
                rowpB[c1] = bB[r] + bias1;
            }
        };
#pragma unroll 1
        for (int np2 = 0; np2 < 5; ++np2) {
            const int t = np2 * 4;
#pragma unroll
            for (int ks = 0; ks < KS; ++ks) {
                f2[ks] = *(const short8*)(base + (size_t)((t + 2) * KS + ks) * 1024);
                f3[ks] = *(const short8*)(base + (size_t)((t + 3) * KS + ks) * 1024);
            }
            {
                f32x4 a0A = {0,0,0,0}, a0B = {0,0,0,0}, a1A = {0,0,0,0}, a1B = {0,0,0,0};
#pragma unroll
                for (int ks = 0; ks < KS; ++ks) {
                    a0A = __builtin_amdgcn_mfma_f32_16x16x32_bf16(aofA[ks], f0[ks], a0A, 0, 0, 0);
                    a0B = __builtin_amdgcn_mfma_f32_16x16x32_bf16(aofB[ks], f0[ks], a0B, 0, 0, 0);
                    a1A = __builtin_amdgcn_mfma_f32_16x16x32_bf16(aofA[ks], f1[ks], a1A, 0, 0, 0);
                    a1B = __builtin_amdgcn_mfma_f32_16x16x32_bf16(aofB[ks], f1[ks], a1B, 0, 0, 0);
                }
                outStore2(t, a0A, a1A, a0B, a1B);
            }
            if (np2 < 4) {
#pragma unroll
                for (int ks = 0; ks < KS; ++ks) {
                    f0[ks] = *(const short8*)(base + (size_t)((t + 4) * KS + ks) * 1024);
                    f1[ks] = *(const short8*)(base + (size_t)((t + 5) * KS + ks) * 1024);
                }
            }
            {
                f32x4 a2A = {0,0,0,0}, a2B = {0,0,0,0}, a3A = {0,0,0,0}, a3B = {0,0,0,0};
#pragma unroll
                for (int ks = 0; ks < KS; ++ks) {
                    a2A = __builtin_amdgcn_mfma_f32_16x16x32_bf16(aofA[ks], f2[ks], a2A, 0, 0, 0);
                    a2B = __builtin_amdgcn_mfma_f32_16x16x32_bf16(aofB[ks], f2[ks], a2B, 0, 0, 0);
                    a3A = __builtin_amdgcn_mfma_f32_16x16x32_bf16(aofA[ks], f3[ks], a3A, 0, 0, 0);
                    a3B = __builtin_amdgcn_mfma_f32_16x16x32_bf16(aofB[ks], f3[ks], a3B, 0, 0, 0);
                }
                outStore2(t + 2, a2A, a3A, a2B, a3B);
            }
        }
    }
}

extern "C" void kernel_launch(void* const* d_in, const int* in_sizes, int n_in,
                              void* d_out, int out_size, void* d_ws, size_t ws_size,
                              hipStream_t stream) {
    const float* hs = (const float*)d_in[0];
    const float* Wq = (const float*)d_in[1];
    const float* Wk = (const float*)d_in[2];
    const float* Wv = (const float*)d_in[3];
    const float* Wo = (const float*)d_in[4];
    const float* bo = (const float*)d_in[5];
    float* out = (float*)d_out;
    char* wpk = (char*)d_ws;   // 4*200*1024 = 819200 B of packed bf16 weights

    pack_weights_kernel<<<dim3((4 * NT * KS * 64 + 255) / 256), dim3(256), 0, stream>>>(
        Wq, Wk, Wv, Wo, wpk);

    const int lds = 2 * 40960;   // 81920 B -> 2 blocks/CU (4 waves/CU)
    (void)hipFuncSetAttribute((const void*)temporal_attn_kernel,
                              hipFuncAttributeMaxDynamicSharedMemorySize, lds);
    temporal_attn_kernel<<<dim3(NSEQ / 4), dim3(THREADS), lds, stream>>>(
        hs, wpk, bo, out);
}